// Round 14
// baseline (161.537 us; speedup 1.0000x reference)
//
#include <hip/hip_runtime.h>
#include <hip/hip_bf16.h>
#include <stdint.h>

// B=1024, D_IN=2048, D_H=4096, D_OUT=2048, D_INT=1024
// r13 skeleton (best: 155.5us) + gemm_sp rebuilt: BK=32, 4-buffer (64KB ->
// still 2 blocks/CU), 3-deep prefetch with counted vmcnt (8/4/0) -- deep
// pipeline AND block-level TLP combined for the first time.

typedef __attribute__((ext_vector_type(8))) short bf16x8;   // 8 bf16 (4 VGPRs)
typedef __attribute__((ext_vector_type(8))) short short8;
typedef __attribute__((ext_vector_type(4))) float f32x4;

__device__ __forceinline__ ushort f2bf(float f) {           // RNE f32->bf16
  union { float f; uint32_t u; } v; v.f = f;
  return (ushort)((v.u + 0x7FFFu + ((v.u >> 16) & 1u)) >> 16);
}
__device__ __forceinline__ float bf2f(ushort u) {
  union { uint32_t u; float f; } v; v.u = (uint32_t)u << 16; return v.f;
}

__device__ __forceinline__ void gload_lds16(const void* g, void* l) {
  __builtin_amdgcn_global_load_lds(
      (const __attribute__((address_space(1))) void*)g,
      (__attribute__((address_space(3))) void*)l, 16, 0, 0);
}

__device__ __forceinline__ void wait_vm8()  { asm volatile("s_waitcnt vmcnt(8)"  ::: "memory"); }
__device__ __forceinline__ void wait_vm4()  { asm volatile("s_waitcnt vmcnt(4)"  ::: "memory"); }
__device__ __forceinline__ void wait_vm0()  { asm volatile("s_waitcnt vmcnt(0)"  ::: "memory"); }
__device__ __forceinline__ void wait_lgkm0(){ asm volatile("s_waitcnt lgkmcnt(0)" ::: "memory"); }
__device__ __forceinline__ void barrier_raw(){ asm volatile("s_barrier" ::: "memory"); }
// barrier that does NOT drain vmcnt (keeps global prefetch loads in flight)
__device__ __forceinline__ void lds_barrier() {
  wait_lgkm0();
  barrier_raw();
  __builtin_amdgcn_sched_barrier(0);
}

template <int NN>
__device__ __forceinline__ void wht_inreg(float* v) {
#pragma unroll
  for (int h = 1; h < NN; h <<= 1)
#pragma unroll
    for (int g = 0; g < NN; g += (h << 1))
#pragma unroll
      for (int k = 0; k < h; ++k) {
        float a = v[g + k], b = v[g + k + h];
        v[g + k] = a + b; v[g + k + h] = a - b;
      }
}

// ---------------- prep: fused  (a) x f32->bf16 cvt [blocks 0..2047]
//                               (b) t = WHT_1024(BB*V) for W1/W2 [2048..2049]
//                               (c) full bias fastfood b1/b2 [2050..2051]
__global__ __launch_bounds__(256) void prep(
    const float4* __restrict__ x4, ushort4* __restrict__ xb4,
    const float* __restrict__ V,
    const float* __restrict__ BBW1, const float* __restrict__ BBW2,
    float* __restrict__ t1, float* __restrict__ t2,
    const float* __restrict__ BBb1, const int* __restrict__ Pib1,
    const float* __restrict__ GGb1, const float* __restrict__ b10,
    const float* __restrict__ BBb2, const int* __restrict__ Pib2,
    const float* __restrict__ GGb2, const float* __restrict__ b20,
    float* __restrict__ ob1, float* __restrict__ ob2) {
  __shared__ float ts[1024];
  __shared__ float zs[4096];
  __shared__ float red[4];
  const int bid = blockIdx.x;
  const int tid = threadIdx.x;

  if (bid < 2048) {                       // role (a): cvt
    int i = bid * 256 + tid;
    float4 v = x4[i];
    ushort4 o;
    o.x = f2bf(v.x); o.y = f2bf(v.y); o.z = f2bf(v.z); o.w = f2bf(v.w);
    xb4[i] = o;
    return;
  }

  if (bid < 2050) {                       // role (b): make_t
    const int which = bid - 2048;
    const float* BB = which ? BBW2 : BBW1;
    float* t = which ? t2 : t1;
    for (int i = tid; i < 1024; i += 256) ts[i] = BB[i] * V[i];
    for (int st = 0; st < 10; ++st) {
      int half = 1 << st;
      __syncthreads();
      for (int j = tid; j < 512; j += 256) {
        int p = ((j >> st) << (st + 1)) | (j & (half - 1));
        float a = ts[p], b = ts[p + half];
        ts[p] = a + b; ts[p + half] = a - b;
      }
    }
    __syncthreads();
    for (int i = tid; i < 1024; i += 256) t[i] = ts[i];
    return;
  }

  // role (c): bias fastfood
  {
    const int which = bid - 2050;
    const int L = which ? 2048 : 4096;
    const float* BB = which ? BBb2 : BBb1;
    const int* Pi = which ? Pib2 : Pib1;
    const float* GG = which ? GGb2 : GGb1;
    const float* b0 = which ? b20 : b10;
    float* ob = which ? ob2 : ob1;

    for (int i = tid; i < 1024; i += 256) ts[i] = BB[i] * V[i];
    for (int st = 0; st < 10; ++st) {
      int half = 1 << st;
      __syncthreads();
      for (int j = tid; j < 512; j += 256) {
        int p = ((j >> st) << (st + 1)) | (j & (half - 1));
        float a = ts[p], b = ts[p + half];
        ts[p] = a + b; ts[p + half] = a - b;
      }
    }
    __syncthreads();
    float gsum = 0.f;
    for (int i = tid; i < L; i += 256) {
      int pi = Pi[i];
      float g = GG[i];
      gsum += g * g;
      zs[i] = ts[pi & 1023] * g;
    }
    for (int o = 32; o > 0; o >>= 1) gsum += __shfl_down(gsum, o);
    if ((tid & 63) == 0) red[tid >> 6] = gsum;
    __syncthreads();
    float ssum = red[0] + red[1] + red[2] + red[3];
    for (int st = 0; (1 << st) < L; ++st) {
      int half = 1 << st;
      __syncthreads();
      for (int j = tid; j < (L >> 1); j += 256) {
        int p = ((j >> st) << (st + 1)) | (j & (half - 1));
        float a = zs[p], b = zs[p + half];
        zs[p] = a + b; zs[p + half] = a - b;
      }
    }
    __syncthreads();
    float scale = rsqrtf((float)L * ssum);
    for (int i = tid; i < L; i += 256) ob[i] = b0[i] + zs[i] * scale;
  }
}

// ---------------- pass 1 (both weights): z = t[Pi&1023]*GG, WHT_8192 on
// contiguous 8192-chunks (bits 0..12) via radix 32(b3-7)/32(b8-12)/8(b0-2)
// register passes; skewed f32 LDS slot = i + (i>>5) keeps all phases <=2-way.
// [r3/r8/r12-proven; sits at the gather-stream floor (~53us, 8 variants)]
__global__ __launch_bounds__(256) void ff_pass1(
    const int* __restrict__ Pi1, const float* __restrict__ GG1,
    const int* __restrict__ Pi2, const float* __restrict__ GG2,
    const float* __restrict__ t1, const float* __restrict__ t2,
    ushort* __restrict__ inter1, ushort* __restrict__ inter2,
    float* __restrict__ partials) {
  __shared__ float ts[1024];
  __shared__ float zs[8448];        // 8192 + skew
  __shared__ float red[4];
  int tid = threadIdx.x;
  int wsel = blockIdx.x >> 10;
  int blk = blockIdx.x & 1023;
  const int* Pi = wsel ? Pi2 : Pi1;
  const float* GG = wsel ? GG2 : GG1;
  const float* t = wsel ? t2 : t1;
  ushort* inter = wsel ? inter2 : inter1;
  size_t base = (size_t)blk * 8192;

  for (int i = tid; i < 1024; i += 256) ts[i] = t[i];
  __syncthreads();

  const int4* Pi4 = (const int4*)(Pi + base);
  const float4* GG4 = (const float4*)(GG + base);
  float gsum = 0.f;
#pragma unroll
  for (int q = 0; q < 8; ++q) {
    int u = (q << 8) + tid;          // 0..2047
    int4 p4 = Pi4[u];
    float4 g4 = GG4[u];
    gsum += g4.x * g4.x + g4.y * g4.y + g4.z * g4.z + g4.w * g4.w;
    int i0 = u << 2;
    float4 z;
    z.x = ts[p4.x & 1023] * g4.x;
    z.y = ts[p4.y & 1023] * g4.y;
    z.z = ts[p4.z & 1023] * g4.z;
    z.w = ts[p4.w & 1023] * g4.w;
    *(float4*)&zs[i0 + (i0 >> 5)] = z;
  }
  for (int o = 32; o > 0; o >>= 1) gsum += __shfl_down(gsum, o);
  if ((tid & 63) == 0) red[tid >> 6] = gsum;
  __syncthreads();
  if (tid == 0) partials[blockIdx.x] = red[0] + red[1] + red[2] + red[3];

  float v[32];
  // pass A: bits 3-7
  {
    int o = (tid & 7) | ((tid >> 3) << 8);
#pragma unroll
    for (int r = 0; r < 32; ++r) { int i = o + (r << 3); v[r] = zs[i + (i >> 5)]; }
    wht_inreg<32>(v);
#pragma unroll
    for (int r = 0; r < 32; ++r) { int i = o + (r << 3); zs[i + (i >> 5)] = v[r]; }
  }
  __syncthreads();
  // pass B: bits 8-12
  {
#pragma unroll
    for (int r = 0; r < 32; ++r) { int i = tid | (r << 8); v[r] = zs[i + (i >> 5)]; }
    wht_inreg<32>(v);
#pragma unroll
    for (int r = 0; r < 32; ++r) { int i = tid | (r << 8); zs[i + (i >> 5)] = v[r]; }
  }
  __syncthreads();
  // pass C: bits 0-2 (4 runs of 8) + coalesced short8 stores
  {
    int tp = ((tid & 63) << 3) | ((tid >> 6) << 11);
#pragma unroll
    for (int j = 0; j < 4; ++j)
#pragma unroll
      for (int k = 0; k < 8; ++k) { int i = tp + (j << 9) + k; v[(j << 3) + k] = zs[i + (i >> 5)]; }
#pragma unroll
    for (int j = 0; j < 4; ++j) wht_inreg<8>(v + (j << 3));
#pragma unroll
    for (int j = 0; j < 4; ++j) {
      short8 s;
#pragma unroll
      for (int k = 0; k < 8; ++k) s[k] = (short)f2bf(v[(j << 3) + k]);
      *(short8*)(inter + base + tp + (j << 9)) = s;
    }
  }
}

// ---------------- pass 2 (both weights): WHT_1024 over h (global bits 13..22,
// stride 8192) on a [1024 rows x 64 cols] bf16 LDS tile, W0 register-prefetch
// across lgkm-only barriers. [r13-proven]
__global__ __launch_bounds__(512) void ff_pass2(
    const ushort* __restrict__ inter1, const ushort* __restrict__ inter2,
    const float* __restrict__ W01, const float* __restrict__ W02,
    const float* __restrict__ partials,
    ushort* __restrict__ W1b, ushort* __restrict__ W2b) {
  __shared__ ushort tile[65536];          // 128 KB
  __shared__ float red[8];
  const int tid = threadIdx.x;
  const int wsel = blockIdx.x >> 7;
  const int cb = (blockIdx.x & 127) << 6;
  const ushort* __restrict__ inter = wsel ? inter2 : inter1;
  const float* __restrict__ W0 = wsel ? W02 : W01;
  ushort* __restrict__ Wb = wsel ? W2b : W1b;
  char* tb = (char*)tile;

  float s = partials[(wsel << 10) + tid] + partials[(wsel << 10) + tid + 512];
  for (int o = 32; o > 0; o >>= 1) s += __shfl_down(s, o);
  if ((tid & 63) == 0) red[tid >> 6] = s;

  // phase 1: coalesced row loads (128 B/lane/row), swizzled LDS stores
#pragma unroll
  for (int h = 0; h < 2; ++h) {
    int r = tid + (h << 9);
    const ushort* gp = inter + ((size_t)r << 13) + cb;
#pragma unroll
    for (int j = 0; j < 8; ++j) {
      short8 d = *(const short8*)(gp + (j << 3));
      *(short8*)(tb + (r << 7) + ((j ^ (r & 7)) << 4)) = d;
    }
  }
  // W0 prefetch, h=0 rows: stays in flight across passA + passB
  float4 w0a0[8], w0b0[8];
  {
    const size_t gb = ((size_t)tid << 13) + cb;
#pragma unroll
    for (int j = 0; j < 8; ++j) {
      w0a0[j] = *(const float4*)(W0 + gb + (j << 3));
      w0b0[j] = *(const float4*)(W0 + gb + (j << 3) + 4);
    }
  }
  lds_barrier();                          // lgkm only: W0 loads NOT drained
  float ssum = 0.f;
#pragma unroll
  for (int k = 0; k < 8; ++k) ssum += red[k];
  const float sc = rsqrtf(8388608.f * ssum);

  const int p = tid & 31;                 // col pair 2p
  const int j0 = p >> 2;                  // granule index
  const int ob = (p & 3) << 2;            // byte offset within granule
  // pass A: rows 32*ge + r  (two sweeps)
#pragma unroll
  for (int swp = 0; swp < 2; ++swp) {
    const int ge = (tid >> 5) + (swp << 4);
    float va[32], vb[32];
#pragma unroll
    for (int r = 0; r < 32; ++r) {
      int row = (ge << 5) + r;
      ushort2 u = *(const ushort2*)(tb + (row << 7) + ((j0 ^ (row & 7)) << 4) + ob);
      va[r] = bf2f(u.x); vb[r] = bf2f(u.y);
    }
    wht_inreg<32>(va); wht_inreg<32>(vb);
#pragma unroll
    for (int r = 0; r < 32; ++r) {
      int row = (ge << 5) + r;
      ushort2 u; u.x = f2bf(va[r]); u.y = f2bf(vb[r]);
      *(ushort2*)(tb + (row << 7) + ((j0 ^ (row & 7)) << 4) + ob) = u;
    }
  }
  lds_barrier();
  // pass B: rows ge + 32*r
#pragma unroll
  for (int swp = 0; swp < 2; ++swp) {
    const int ge = (tid >> 5) + (swp << 4);
    float va[32], vb[32];
#pragma unroll
    for (int r = 0; r < 32; ++r) {
      int row = ge + (r << 5);
      ushort2 u = *(const ushort2*)(tb + (row << 7) + ((j0 ^ (row & 7)) << 4) + ob);
      va[r] = bf2f(u.x); vb[r] = bf2f(u.y);
    }
    wht_inreg<32>(va); wht_inreg<32>(vb);
#pragma unroll
    for (int r = 0; r < 32; ++r) {
      int row = ge + (r << 5);
      ushort2 u; u.x = f2bf(va[r]); u.y = f2bf(vb[r]);
      *(ushort2*)(tb + (row << 7) + ((j0 ^ (row & 7)) << 4) + ob) = u;
    }
  }
  // W0 prefetch, h=1 rows: in flight across the barrier + epilogue h=0
  float4 w0a1[8], w0b1[8];
  {
    const size_t gb = ((size_t)(tid + 512) << 13) + cb;
#pragma unroll
    for (int j = 0; j < 8; ++j) {
      w0a1[j] = *(const float4*)(W0 + gb + (j << 3));
      w0b1[j] = *(const float4*)(W0 + gb + (j << 3) + 4);
    }
  }
  lds_barrier();
  // epilogue: W = W0 + m5*sc -> bf16 (full-line writes), W0 from registers
  {
    const int r = tid;
    const size_t gb = ((size_t)r << 13) + cb;
#pragma unroll
    for (int j = 0; j < 8; ++j) {
      short8 d = *(const short8*)(tb + (r << 7) + ((j ^ (r & 7)) << 4));
      short8 o;
      o[0] = (short)f2bf(bf2f((ushort)d[0]) * sc + w0a0[j].x);
      o[1] = (short)f2bf(bf2f((ushort)d[1]) * sc + w0a0[j].y);
      o[2] = (short)f2bf(bf2f((ushort)d[2]) * sc + w0a0[j].z);
      o[3] = (short)f2bf(bf2f((ushort)d[3]) * sc + w0a0[j].w);
      o[4] = (short)f2bf(bf2f((ushort)d[4]) * sc + w0b0[j].x);
      o[5] = (short)f2bf(bf2f((ushort)d[5]) * sc + w0b0[j].y);
      o[6] = (short)f2bf(bf2f((ushort)d[6]) * sc + w0b0[j].z);
      o[7] = (short)f2bf(bf2f((ushort)d[7]) * sc + w0b0[j].w);
      *(short8*)(Wb + gb + (j << 3)) = o;
    }
  }
  {
    const int r = tid + 512;
    const size_t gb = ((size_t)r << 13) + cb;
#pragma unroll
    for (int j = 0; j < 8; ++j) {
      short8 d = *(const short8*)(tb + (r << 7) + ((j ^ (r & 7)) << 4));
      short8 o;
      o[0] = (short)f2bf(bf2f((ushort)d[0]) * sc + w0a1[j].x);
      o[1] = (short)f2bf(bf2f((ushort)d[1]) * sc + w0a1[j].y);
      o[2] = (short)f2bf(bf2f((ushort)d[2]) * sc + w0a1[j].z);
      o[3] = (short)f2bf(bf2f((ushort)d[3]) * sc + w0a1[j].w);
      o[4] = (short)f2bf(bf2f((ushort)d[4]) * sc + w0b1[j].x);
      o[5] = (short)f2bf(bf2f((ushort)d[5]) * sc + w0b1[j].y);
      o[6] = (short)f2bf(bf2f((ushort)d[6]) * sc + w0b1[j].z);
      o[7] = (short)f2bf(bf2f((ushort)d[7]) * sc + w0b1[j].w);
      *(short8*)(Wb + gb + (j << 3)) = o;
    }
  }
}

// ---------------- gemm_sp: C-partial = A*B^T over K-slice blockIdx.z.
// 128x128 tile, BK=32, 4 waves (2x2), 4-buffer LDS (64 KB -> 2 blocks/CU),
// 3-deep prefetch with counted vmcnt(8/4/0) -- loads stay in flight across
// barriers AND two blocks co-schedule per CU. Swizzle: granule ^= (row>>1)&3
// (source-preswizzled for linear gload_lds dest; same XOR on ds_read; lanes
// 0-15 cover all 8 bank-groups = conflict-free). bf16 partial plane P[z].
template <int NT>
__global__ __launch_bounds__(256) void gemm_sp(
    const ushort* __restrict__ A, const ushort* __restrict__ B,
    ushort* __restrict__ P0, ushort* __restrict__ P1,
    ushort* __restrict__ P2, ushort* __restrict__ P3,
    int M, int N, int K) {
  __shared__ ushort As[4][4096];
  __shared__ ushort Bs[4][4096];
  const int tid = threadIdx.x;
  const int w = tid >> 6, l = tid & 63;
  const int wr = w >> 1, wc = w & 1;
  const int brow = blockIdx.y << 7, bcol = blockIdx.x << 7;
  const int srow = tid >> 2;                     // staging row 0..63
  const int sg = tid & 3;                        // granule 0..3
  const int csrc = (sg ^ ((srow >> 1) & 3)) << 3;  // pre-swizzled source col
  const int l15 = l & 15;
  const int c8 = l >> 4;                         // fragment granule 0..3
  const int gx = (l15 >> 1) & 3;                 // (row>>1)&3 per lane
  const int z = blockIdx.z;
  const int kb = z * (NT << 5);
  ushort* __restrict__ P = z == 0 ? P0 : z == 1 ? P1 : z == 2 ? P2 : P3;
  f32x4 acc[4][4] = {};

  const ushort* pa = A + (size_t)(brow + srow) * K + kb + csrc;
  const ushort* pb = B + (size_t)(bcol + srow) * K + kb + csrc;
  const size_t K64 = (size_t)K << 6;             // +64 rows (ushorts)

#define STAGE(buf, tt)                                                \
  {                                                                   \
    const ushort* qa = pa + ((tt) << 5);                              \
    const ushort* qb = pb + ((tt) << 5);                              \
    gload_lds16(qa,       (char*)As[buf] + (tid << 4));               \
    gload_lds16(qa + K64, (char*)As[buf] + 4096 + (tid << 4));        \
    gload_lds16(qb,       (char*)Bs[buf] + (tid << 4));               \
    gload_lds16(qb + K64, (char*)Bs[buf] + 4096 + (tid << 4));        \
  }

  STAGE(0, 0); STAGE(1, 1); STAGE(2, 2);         // 12 outstanding/thread
  for (int t = 0; t < NT; ++t) {
    if (t < NT - 2) wait_vm8();                  // stage t landed; 2 in flight
    else if (t == NT - 2) wait_vm4();
    else wait_vm0();
    barrier_raw();
    if (t + 3 < NT) STAGE((t + 3) & 3, t + 3);   // overwrites buf[(t-1)&3]
    const ushort* Acur = As[t & 3];
    const ushort* Bcur = Bs[t & 3];
    bf16x8 af[4], bfr[4];
#pragma unroll
    for (int m = 0; m < 4; ++m) {
      int ra = (wr << 6) + (m << 4) + l15;
      af[m] = *(const bf16x8*)&Acur[(ra << 5) + ((c8 ^ gx) << 3)];
    }
#pragma unroll
    for (int n = 0; n < 4; ++n) {
      int rb = (wc << 6) + (n << 4) + l15;
      bfr[n] = *(const bf16x8*)&Bcur[(rb << 5) + ((c8 ^ gx) << 3)];
    }
    wait_lgkm0();
#pragma unroll
    for (int m = 0; m < 4; ++m)
#pragma unroll
      for (int n = 0; n < 4; ++n)
        acc[m][n] = __builtin_amdgcn_mfma_f32_16x16x32_bf16(af[m], bfr[n], acc[m][n], 0, 0, 0);
  }
#undef STAGE

#pragma unroll
  for (int n = 0; n < 4; ++n) {
    int col = bcol + (wc << 6) + (n << 4) + l15;
#pragma unroll
    for (int m = 0; m < 4; ++m) {
      int row0 = brow + (wr << 6) + (m << 4) + ((l >> 4) << 2);
#pragma unroll
      for (int j = 0; j < 4; ++j)
        P[(size_t)(row0 + j) * N + col] = f2bf(acc[m][n][j]);
    }
  }
}

// ---------------- h = relu(G0 + G1 + b1)  (1024x4096, bf16 planes -> bf16)
__global__ __launch_bounds__(256) void hfuse(
    const ushort4* __restrict__ G0, const ushort4* __restrict__ G1,
    const float* __restrict__ b1, ushort4* __restrict__ hb) {
  int i = blockIdx.x * 256 + threadIdx.x;       // 1048576 u4
  ushort4 a = G0[i], b = G1[i];
  const float4 bv = *(const float4*)(b1 + ((i & 1023) << 2));
  ushort4 o;
  o.x = f2bf(fmaxf(bf2f(a.x) + bf2f(b.x) + bv.x, 0.f));
  o.y = f2bf(fmaxf(bf2f(a.y) + bf2f(b.y) + bv.y, 0.f));
  o.z = f2bf(fmaxf(bf2f(a.z) + bf2f(b.z) + bv.z, 0.f));
  o.w = f2bf(fmaxf(bf2f(a.w) + bf2f(b.w) + bv.w, 0.f));
  hb[i] = o;
}

// ---------------- out = Q0+Q1+Q2+Q3 + b2   (1024x2048, bf16 planes -> f32)
__global__ __launch_bounds__(256) void reduce_out4(
    const ushort4* __restrict__ Q0, const ushort4* __restrict__ Q1,
    const ushort4* __restrict__ Q2, const ushort4* __restrict__ Q3,
    const float* __restrict__ b2, float4* __restrict__ out) {
  int i = blockIdx.x * 256 + threadIdx.x;       // 524288 u4
  ushort4 a = Q0[i], b = Q1[i], c = Q2[i], d = Q3[i];
  const float4 bb = *(const float4*)(b2 + ((i & 511) << 2));
  float4 o;
  o.x = bf2f(a.x) + bf2f(b.x) + bf2f(c.x) + bf2f(d.x) + bb.x;
  o.y = bf2f(a.y) + bf2f(b.y) + bf2f(c.y) + bf2f(d.y) + bb.y;
  o.z = bf2f(a.z) + bf2f(b.z) + bf2f(c.z) + bf2f(d.z) + bb.z;
  o.w = bf2f(a.w) + bf2f(b.w) + bf2f(c.w) + bf2f(d.w) + bb.w;
  out[i] = o;
}

extern "C" void kernel_launch(void* const* d_in, const int* in_sizes, int n_in,
                              void* d_out, int out_size, void* d_ws, size_t ws_size,
                              hipStream_t stream) {
  const float* x     = (const float*)d_in[0];
  const float* V     = (const float*)d_in[1];
  const float* W1_0  = (const float*)d_in[2];
  const float* b1_0  = (const float*)d_in[3];
  const float* W2_0  = (const float*)d_in[4];
  const float* b2_0  = (const float*)d_in[5];
  const float* BB_W1 = (const float*)d_in[6];
  const int*   Pi_W1 = (const int*)d_in[7];
  const float* GG_W1 = (const float*)d_in[8];
  const float* BB_b1 = (const float*)d_in[9];
  const int*   Pi_b1 = (const int*)d_in[10];
  const float* GG_b1 = (const float*)d_in[11];
  const float* BB_W2 = (const float*)d_in[12];
  const int*   Pi_W2 = (const int*)d_in[13];
  const float* GG_W2 = (const float*)d_in[14];
  const float* BB_b2 = (const float*)d_in[15];
  const int*   Pi_b2 = (const int*)d_in[16];
  const float* GG_b2 = (const float*)d_in[17];
  float* out = (float*)d_out;

  const size_t MB = 1048576ull;
  char* ws = (char*)d_ws;
  // inter1@0 / inter2@16 die after ff_pass2; G planes (gemm1, 8MB each) alias
  // inter1; Q planes (gemm2, 4MB each) alias inter2.
  ushort* inter1 = (ushort*)(ws);
  ushort* G0     = (ushort*)(ws);
  ushort* G1     = (ushort*)(ws + 8 * MB);
  ushort* inter2 = (ushort*)(ws + 16 * MB);
  ushort* Q0     = (ushort*)(ws + 16 * MB);
  ushort* Q1     = (ushort*)(ws + 20 * MB);
  ushort* Q2     = (ushort*)(ws + 24 * MB);
  ushort* Q3     = (ushort*)(ws + 28 * MB);
  ushort* W1b    = (ushort*)(ws + 32 * MB);
  ushort* W2b    = (ushort*)(ws + 48 * MB);
  ushort* xb     = (ushort*)(ws + 64 * MB);
  ushort* hb     = (ushort*)(ws + 68 * MB);
  char*   S      = ws + 76 * MB;
  float*  t1     = (float*)(S);
  float*  t2     = (float*)(S + 4096);
  float*  b1     = (float*)(S + 8192);
  float*  b2     = (float*)(S + 8192 + 16384);
  float*  parts  = (float*)(S + 8192 + 16384 + 8192);   // 2048 floats

  prep<<<2052, 256, 0, stream>>>((const float4*)x, (ushort4*)xb, V,
                                 BB_W1, BB_W2, t1, t2,
                                 BB_b1, Pi_b1, GG_b1, b1_0,
                                 BB_b2, Pi_b2, GG_b2, b2_0, b1, b2);

  ff_pass1<<<2048, 256, 0, stream>>>(Pi_W1, GG_W1, Pi_W2, GG_W2, t1, t2,
                                     inter1, inter2, parts);
  ff_pass2<<<256, 512, 0, stream>>>(inter1, inter2, W1_0, W2_0, parts, W1b, W2b);

  // gemm1: x @ W1b^T, K=2048 split-K2 -> G0,G1 (512 blocks, 2/CU)
  gemm_sp<32><<<dim3(32, 8, 2), 256, 0, stream>>>(xb, W1b, G0, G1, nullptr, nullptr,
                                                  1024, 4096, 2048);
  // h = relu(G0+G1+b1)
  hfuse<<<4096, 256, 0, stream>>>((const ushort4*)G0, (const ushort4*)G1, b1,
                                  (ushort4*)hb);
  // gemm2: h @ W2b^T, K=4096 split-K4 -> Q0..Q3 (512 blocks, 2/CU)
  gemm_sp<32><<<dim3(16, 8, 4), 256, 0, stream>>>(hb, W2b, Q0, Q1, Q2, Q3,
                                                  1024, 2048, 4096);
  // out = Q0+Q1+Q2+Q3 + b2
  reduce_out4<<<2048, 256, 0, stream>>>((const ushort4*)Q0, (const ushort4*)Q1,
                                        (const ushort4*)Q2, (const ushort4*)Q3,
                                        b2, (float4*)out);
}

// Round 15
// 154.472 us; speedup vs baseline: 1.0457x; 1.0457x over previous
//
#include <hip/hip_runtime.h>
#include <hip/hip_bf16.h>
#include <stdint.h>

// B=1024, D_IN=2048, D_H=4096, D_OUT=2048, D_INT=1024
// r13 configuration restored verbatim (measured best: 155.5us).
// r14's BK=32 4-buffer gemm regressed (161.5) -> BK=64 2-buffer + 2 blocks/CU
// is the best-measured GEMM point; pass1 sits at the gather-stream invariant
// (~54us across 8 structural variants); pass2 has W0 register-prefetch.

typedef __attribute__((ext_vector_type(8))) short bf16x8;   // 8 bf16 (4 VGPRs)
typedef __attribute__((ext_vector_type(8))) short short8;
typedef __attribute__((ext_vector_type(4))) float f32x4;

__device__ __forceinline__ ushort f2bf(float f) {           // RNE f32->bf16
  union { float f; uint32_t u; } v; v.f = f;
  return (ushort)((v.u + 0x7FFFu + ((v.u >> 16) & 1u)) >> 16);
}
__device__ __forceinline__ float bf2f(ushort u) {
  union { uint32_t u; float f; } v; v.u = (uint32_t)u << 16; return v.f;
}

__device__ __forceinline__ void gload_lds16(const void* g, void* l) {
  __builtin_amdgcn_global_load_lds(
      (const __attribute__((address_space(1))) void*)g,
      (__attribute__((address_space(3))) void*)l, 16, 0, 0);
}

__device__ __forceinline__ void wait_vm0()  { asm volatile("s_waitcnt vmcnt(0)"  ::: "memory"); }
__device__ __forceinline__ void wait_lgkm0(){ asm volatile("s_waitcnt lgkmcnt(0)" ::: "memory"); }
__device__ __forceinline__ void barrier_raw(){ asm volatile("s_barrier" ::: "memory"); }
// barrier that does NOT drain vmcnt (keeps global prefetch loads in flight)
__device__ __forceinline__ void lds_barrier() {
  wait_lgkm0();
  barrier_raw();
  __builtin_amdgcn_sched_barrier(0);
}

template <int NN>
__device__ __forceinline__ void wht_inreg(float* v) {
#pragma unroll
  for (int h = 1; h < NN; h <<= 1)
#pragma unroll
    for (int g = 0; g < NN; g += (h << 1))
#pragma unroll
      for (int k = 0; k < h; ++k) {
        float a = v[g + k], b = v[g + k + h];
        v[g + k] = a + b; v[g + k + h] = a - b;
      }
}

// ---------------- prep: fused  (a) x f32->bf16 cvt [blocks 0..2047]
//                               (b) t = WHT_1024(BB*V) for W1/W2 [2048..2049]
//                               (c) full bias fastfood b1/b2 [2050..2051]
__global__ __launch_bounds__(256) void prep(
    const float4* __restrict__ x4, ushort4* __restrict__ xb4,
    const float* __restrict__ V,
    const float* __restrict__ BBW1, const float* __restrict__ BBW2,
    float* __restrict__ t1, float* __restrict__ t2,
    const float* __restrict__ BBb1, const int* __restrict__ Pib1,
    const float* __restrict__ GGb1, const float* __restrict__ b10,
    const float* __restrict__ BBb2, const int* __restrict__ Pib2,
    const float* __restrict__ GGb2, const float* __restrict__ b20,
    float* __restrict__ ob1, float* __restrict__ ob2) {
  __shared__ float ts[1024];
  __shared__ float zs[4096];
  __shared__ float red[4];
  const int bid = blockIdx.x;
  const int tid = threadIdx.x;

  if (bid < 2048) {                       // role (a): cvt
    int i = bid * 256 + tid;
    float4 v = x4[i];
    ushort4 o;
    o.x = f2bf(v.x); o.y = f2bf(v.y); o.z = f2bf(v.z); o.w = f2bf(v.w);
    xb4[i] = o;
    return;
  }

  if (bid < 2050) {                       // role (b): make_t
    const int which = bid - 2048;
    const float* BB = which ? BBW2 : BBW1;
    float* t = which ? t2 : t1;
    for (int i = tid; i < 1024; i += 256) ts[i] = BB[i] * V[i];
    for (int st = 0; st < 10; ++st) {
      int half = 1 << st;
      __syncthreads();
      for (int j = tid; j < 512; j += 256) {
        int p = ((j >> st) << (st + 1)) | (j & (half - 1));
        float a = ts[p], b = ts[p + half];
        ts[p] = a + b; ts[p + half] = a - b;
      }
    }
    __syncthreads();
    for (int i = tid; i < 1024; i += 256) t[i] = ts[i];
    return;
  }

  // role (c): bias fastfood
  {
    const int which = bid - 2050;
    const int L = which ? 2048 : 4096;
    const float* BB = which ? BBb2 : BBb1;
    const int* Pi = which ? Pib2 : Pib1;
    const float* GG = which ? GGb2 : GGb1;
    const float* b0 = which ? b20 : b10;
    float* ob = which ? ob2 : ob1;

    for (int i = tid; i < 1024; i += 256) ts[i] = BB[i] * V[i];
    for (int st = 0; st < 10; ++st) {
      int half = 1 << st;
      __syncthreads();
      for (int j = tid; j < 512; j += 256) {
        int p = ((j >> st) << (st + 1)) | (j & (half - 1));
        float a = ts[p], b = ts[p + half];
        ts[p] = a + b; ts[p + half] = a - b;
      }
    }
    __syncthreads();
    float gsum = 0.f;
    for (int i = tid; i < L; i += 256) {
      int pi = Pi[i];
      float g = GG[i];
      gsum += g * g;
      zs[i] = ts[pi & 1023] * g;
    }
    for (int o = 32; o > 0; o >>= 1) gsum += __shfl_down(gsum, o);
    if ((tid & 63) == 0) red[tid >> 6] = gsum;
    __syncthreads();
    float ssum = red[0] + red[1] + red[2] + red[3];
    for (int st = 0; (1 << st) < L; ++st) {
      int half = 1 << st;
      __syncthreads();
      for (int j = tid; j < (L >> 1); j += 256) {
        int p = ((j >> st) << (st + 1)) | (j & (half - 1));
        float a = zs[p], b = zs[p + half];
        zs[p] = a + b; zs[p + half] = a - b;
      }
    }
    __syncthreads();
    float scale = rsqrtf((float)L * ssum);
    for (int i = tid; i < L; i += 256) ob[i] = b0[i] + zs[i] * scale;
  }
}

// ---------------- pass 1 (both weights): z = t[Pi&1023]*GG, WHT_8192 on
// contiguous 8192-chunks (bits 0..12) via radix 32(b3-7)/32(b8-12)/8(b0-2)
// register passes; skewed f32 LDS slot = i + (i>>5) keeps all phases <=2-way.
// [r3/r8/r12-proven; sits at the gather-stream floor (~53us, 8 variants)]
__global__ __launch_bounds__(256) void ff_pass1(
    const int* __restrict__ Pi1, const float* __restrict__ GG1,
    const int* __restrict__ Pi2, const float* __restrict__ GG2,
    const float* __restrict__ t1, const float* __restrict__ t2,
    ushort* __restrict__ inter1, ushort* __restrict__ inter2,
    float* __restrict__ partials) {
  __shared__ float ts[1024];
  __shared__ float zs[8448];        // 8192 + skew
  __shared__ float red[4];
  int tid = threadIdx.x;
  int wsel = blockIdx.x >> 10;
  int blk = blockIdx.x & 1023;
  const int* Pi = wsel ? Pi2 : Pi1;
  const float* GG = wsel ? GG2 : GG1;
  const float* t = wsel ? t2 : t1;
  ushort* inter = wsel ? inter2 : inter1;
  size_t base = (size_t)blk * 8192;

  for (int i = tid; i < 1024; i += 256) ts[i] = t[i];
  __syncthreads();

  const int4* Pi4 = (const int4*)(Pi + base);
  const float4* GG4 = (const float4*)(GG + base);
  float gsum = 0.f;
#pragma unroll
  for (int q = 0; q < 8; ++q) {
    int u = (q << 8) + tid;          // 0..2047
    int4 p4 = Pi4[u];
    float4 g4 = GG4[u];
    gsum += g4.x * g4.x + g4.y * g4.y + g4.z * g4.z + g4.w * g4.w;
    int i0 = u << 2;
    float4 z;
    z.x = ts[p4.x & 1023] * g4.x;
    z.y = ts[p4.y & 1023] * g4.y;
    z.z = ts[p4.z & 1023] * g4.z;
    z.w = ts[p4.w & 1023] * g4.w;
    *(float4*)&zs[i0 + (i0 >> 5)] = z;
  }
  for (int o = 32; o > 0; o >>= 1) gsum += __shfl_down(gsum, o);
  if ((tid & 63) == 0) red[tid >> 6] = gsum;
  __syncthreads();
  if (tid == 0) partials[blockIdx.x] = red[0] + red[1] + red[2] + red[3];

  float v[32];
  // pass A: bits 3-7
  {
    int o = (tid & 7) | ((tid >> 3) << 8);
#pragma unroll
    for (int r = 0; r < 32; ++r) { int i = o + (r << 3); v[r] = zs[i + (i >> 5)]; }
    wht_inreg<32>(v);
#pragma unroll
    for (int r = 0; r < 32; ++r) { int i = o + (r << 3); zs[i + (i >> 5)] = v[r]; }
  }
  __syncthreads();
  // pass B: bits 8-12
  {
#pragma unroll
    for (int r = 0; r < 32; ++r) { int i = tid | (r << 8); v[r] = zs[i + (i >> 5)]; }
    wht_inreg<32>(v);
#pragma unroll
    for (int r = 0; r < 32; ++r) { int i = tid | (r << 8); zs[i + (i >> 5)] = v[r]; }
  }
  __syncthreads();
  // pass C: bits 0-2 (4 runs of 8) + coalesced short8 stores
  {
    int tp = ((tid & 63) << 3) | ((tid >> 6) << 11);
#pragma unroll
    for (int j = 0; j < 4; ++j)
#pragma unroll
      for (int k = 0; k < 8; ++k) { int i = tp + (j << 9) + k; v[(j << 3) + k] = zs[i + (i >> 5)]; }
#pragma unroll
    for (int j = 0; j < 4; ++j) wht_inreg<8>(v + (j << 3));
#pragma unroll
    for (int j = 0; j < 4; ++j) {
      short8 s;
#pragma unroll
      for (int k = 0; k < 8; ++k) s[k] = (short)f2bf(v[(j << 3) + k]);
      *(short8*)(inter + base + tp + (j << 9)) = s;
    }
  }
}

// ---------------- pass 2 (both weights): WHT_1024 over h (global bits 13..22,
// stride 8192) on a [1024 rows x 64 cols] bf16 LDS tile, W0 register-prefetch
// across lgkm-only barriers. [r13-proven]
__global__ __launch_bounds__(512) void ff_pass2(
    const ushort* __restrict__ inter1, const ushort* __restrict__ inter2,
    const float* __restrict__ W01, const float* __restrict__ W02,
    const float* __restrict__ partials,
    ushort* __restrict__ W1b, ushort* __restrict__ W2b) {
  __shared__ ushort tile[65536];          // 128 KB
  __shared__ float red[8];
  const int tid = threadIdx.x;
  const int wsel = blockIdx.x >> 7;
  const int cb = (blockIdx.x & 127) << 6;
  const ushort* __restrict__ inter = wsel ? inter2 : inter1;
  const float* __restrict__ W0 = wsel ? W02 : W01;
  ushort* __restrict__ Wb = wsel ? W2b : W1b;
  char* tb = (char*)tile;

  float s = partials[(wsel << 10) + tid] + partials[(wsel << 10) + tid + 512];
  for (int o = 32; o > 0; o >>= 1) s += __shfl_down(s, o);
  if ((tid & 63) == 0) red[tid >> 6] = s;

  // phase 1: coalesced row loads (128 B/lane/row), swizzled LDS stores
#pragma unroll
  for (int h = 0; h < 2; ++h) {
    int r = tid + (h << 9);
    const ushort* gp = inter + ((size_t)r << 13) + cb;
#pragma unroll
    for (int j = 0; j < 8; ++j) {
      short8 d = *(const short8*)(gp + (j << 3));
      *(short8*)(tb + (r << 7) + ((j ^ (r & 7)) << 4)) = d;
    }
  }
  // W0 prefetch, h=0 rows: stays in flight across passA + passB
  float4 w0a0[8], w0b0[8];
  {
    const size_t gb = ((size_t)tid << 13) + cb;
#pragma unroll
    for (int j = 0; j < 8; ++j) {
      w0a0[j] = *(const float4*)(W0 + gb + (j << 3));
      w0b0[j] = *(const float4*)(W0 + gb + (j << 3) + 4);
    }
  }
  lds_barrier();                          // lgkm only: W0 loads NOT drained
  float ssum = 0.f;
#pragma unroll
  for (int k = 0; k < 8; ++k) ssum += red[k];
  const float sc = rsqrtf(8388608.f * ssum);

  const int p = tid & 31;                 // col pair 2p
  const int j0 = p >> 2;                  // granule index
  const int ob = (p & 3) << 2;            // byte offset within granule
  // pass A: rows 32*ge + r  (two sweeps)
#pragma unroll
  for (int swp = 0; swp < 2; ++swp) {
    const int ge = (tid >> 5) + (swp << 4);
    float va[32], vb[32];
#pragma unroll
    for (int r = 0; r < 32; ++r) {
      int row = (ge << 5) + r;
      ushort2 u = *(const ushort2*)(tb + (row << 7) + ((j0 ^ (row & 7)) << 4) + ob);
      va[r] = bf2f(u.x); vb[r] = bf2f(u.y);
    }
    wht_inreg<32>(va); wht_inreg<32>(vb);
#pragma unroll
    for (int r = 0; r < 32; ++r) {
      int row = (ge << 5) + r;
      ushort2 u; u.x = f2bf(va[r]); u.y = f2bf(vb[r]);
      *(ushort2*)(tb + (row << 7) + ((j0 ^ (row & 7)) << 4) + ob) = u;
    }
  }
  lds_barrier();
  // pass B: rows ge + 32*r
#pragma unroll
  for (int swp = 0; swp < 2; ++swp) {
    const int ge = (tid >> 5) + (swp << 4);
    float va[32], vb[32];
#pragma unroll
    for (int r = 0; r < 32; ++r) {
      int row = ge + (r << 5);
      ushort2 u = *(const ushort2*)(tb + (row << 7) + ((j0 ^ (row & 7)) << 4) + ob);
      va[r] = bf2f(u.x); vb[r] = bf2f(u.y);
    }
    wht_inreg<32>(va); wht_inreg<32>(vb);
#pragma unroll
    for (int r = 0; r < 32; ++r) {
      int row = ge + (r << 5);
      ushort2 u; u.x = f2bf(va[r]); u.y = f2bf(vb[r]);
      *(ushort2*)(tb + (row << 7) + ((j0 ^ (row & 7)) << 4) + ob) = u;
    }
  }
  // W0 prefetch, h=1 rows: in flight across the barrier + epilogue h=0
  float4 w0a1[8], w0b1[8];
  {
    const size_t gb = ((size_t)(tid + 512) << 13) + cb;
#pragma unroll
    for (int j = 0; j < 8; ++j) {
      w0a1[j] = *(const float4*)(W0 + gb + (j << 3));
      w0b1[j] = *(const float4*)(W0 + gb + (j << 3) + 4);
    }
  }
  lds_barrier();
  // epilogue: W = W0 + m5*sc -> bf16 (full-line writes), W0 from registers
  {
    const int r = tid;
    const size_t gb = ((size_t)r << 13) + cb;
#pragma unroll
    for (int j = 0; j < 8; ++j) {
      short8 d = *(const short8*)(tb + (r << 7) + ((j ^ (r & 7)) << 4));
      short8 o;
      o[0] = (short)f2bf(bf2f((ushort)d[0]) * sc + w0a0[j].x);
      o[1] = (short)f2bf(bf2f((ushort)d[1]) * sc + w0a0[j].y);
      o[2] = (short)f2bf(bf2f((ushort)d[2]) * sc + w0a0[j].z);
      o[3] = (short)f2bf(bf2f((ushort)d[3]) * sc + w0a0[j].w);
      o[4] = (short)f2bf(bf2f((ushort)d[4]) * sc + w0b0[j].x);
      o[5] = (short)f2bf(bf2f((ushort)d[5]) * sc + w0b0[j].y);
      o[6] = (short)f2bf(bf2f((ushort)d[6]) * sc + w0b0[j].z);
      o[7] = (short)f2bf(bf2f((ushort)d[7]) * sc + w0b0[j].w);
      *(short8*)(Wb + gb + (j << 3)) = o;
    }
  }
  {
    const int r = tid + 512;
    const size_t gb = ((size_t)r << 13) + cb;
#pragma unroll
    for (int j = 0; j < 8; ++j) {
      short8 d = *(const short8*)(tb + (r << 7) + ((j ^ (r & 7)) << 4));
      short8 o;
      o[0] = (short)f2bf(bf2f((ushort)d[0]) * sc + w0a1[j].x);
      o[1] = (short)f2bf(bf2f((ushort)d[1]) * sc + w0a1[j].y);
      o[2] = (short)f2bf(bf2f((ushort)d[2]) * sc + w0a1[j].z);
      o[3] = (short)f2bf(bf2f((ushort)d[3]) * sc + w0a1[j].w);
      o[4] = (short)f2bf(bf2f((ushort)d[4]) * sc + w0b1[j].x);
      o[5] = (short)f2bf(bf2f((ushort)d[5]) * sc + w0b1[j].y);
      o[6] = (short)f2bf(bf2f((ushort)d[6]) * sc + w0b1[j].z);
      o[7] = (short)f2bf(bf2f((ushort)d[7]) * sc + w0b1[j].w);
      *(short8*)(Wb + gb + (j << 3)) = o;
    }
  }
}

// ---------------- gemm_sp: C-partial = A*B^T over K-slice blockIdx.z.
// 128x128 tile, BK=64, 4 waves (2x2), 2-buffer LDS (64 KB -> 2 blocks/CU:
// the co-resident block's MFMAs cover this block's vm0/barrier stalls).
// [r12-proven: took total 171->157.6; r14's BK=32 variant regressed]
template <int NT>
__global__ __launch_bounds__(256) void gemm_sp(
    const ushort* __restrict__ A, const ushort* __restrict__ B,
    ushort* __restrict__ P0, ushort* __restrict__ P1,
    ushort* __restrict__ P2, ushort* __restrict__ P3,
    int M, int N, int K) {
  __shared__ ushort As[2][8192];
  __shared__ ushort Bs[2][8192];
  const int tid = threadIdx.x;
  const int w = tid >> 6, l = tid & 63;
  const int wr = w >> 1, wc = w & 1;
  const int brow = blockIdx.y << 7, bcol = blockIdx.x << 7;
  const int lrow = l >> 3;                       // row within 8-row chunk
  const int csrc = ((l & 7) ^ lrow) << 3;        // swizzled source col (ushort)
  const int l15 = l & 15;
  const int x7 = l15 & 7;
  const int z = blockIdx.z;
  const int kb = z * (NT << 6);
  ushort* __restrict__ P = z == 0 ? P0 : z == 1 ? P1 : z == 2 ? P2 : P3;
  f32x4 acc[4][4] = {};

  const ushort* pa = A + (size_t)(brow + (w << 5) + lrow) * K + kb + csrc;
  const ushort* pb = B + (size_t)(bcol + (w << 5) + lrow) * K + kb + csrc;
  const size_t K8 = (size_t)K << 3;

#define STAGE(buf, tt)                                                      \
  {                                                                         \
    const ushort* qa = pa + ((tt) << 6);                                    \
    const ushort* qb = pb + ((tt) << 6);                                    \
    _Pragma("unroll")                                                       \
    for (int i = 0; i < 4; ++i) {                                           \
      gload_lds16(qa + K8 * i, &As[buf][(((w << 2) + i) << 9)]);            \
      gload_lds16(qb + K8 * i, &Bs[buf][(((w << 2) + i) << 9)]);            \
    }                                                                       \
  }

  STAGE(0, 0);
  for (int t = 0; t < NT; ++t) {
    wait_vm0();                               // tile t landed
    barrier_raw();                            // all waves done reading buf[(t+1)&1]
    if (t + 1 < NT) STAGE((t + 1) & 1, t + 1);
    const ushort* Acur = As[t & 1];
    const ushort* Bcur = Bs[t & 1];
    bf16x8 af[2][4], bfr[2][4];
#pragma unroll
    for (int kk = 0; kk < 2; ++kk) {
      int c8 = (kk << 2) + (l >> 4);
#pragma unroll
      for (int m = 0; m < 4; ++m)
        af[kk][m] = *(const bf16x8*)&Acur[(((wr << 6) + (m << 4) + l15) << 6) + ((c8 ^ x7) << 3)];
#pragma unroll
      for (int n = 0; n < 4; ++n)
        bfr[kk][n] = *(const bf16x8*)&Bcur[(((wc << 6) + (n << 4) + l15) << 6) + ((c8 ^ x7) << 3)];
    }
    wait_lgkm0();
#pragma unroll
    for (int kk = 0; kk < 2; ++kk)
#pragma unroll
      for (int m = 0; m < 4; ++m)
#pragma unroll
        for (int n = 0; n < 4; ++n)
          acc[m][n] = __builtin_amdgcn_mfma_f32_16x16x32_bf16(af[kk][m], bfr[kk][n], acc[m][n], 0, 0, 0);
  }
#undef STAGE

#pragma unroll
  for (int n = 0; n < 4; ++n) {
    int col = bcol + (wc << 6) + (n << 4) + l15;
#pragma unroll
    for (int m = 0; m < 4; ++m) {
      int row0 = brow + (wr << 6) + (m << 4) + ((l >> 4) << 2);
#pragma unroll
      for (int j = 0; j < 4; ++j)
        P[(size_t)(row0 + j) * N + col] = f2bf(acc[m][n][j]);
    }
  }
}

// ---------------- h = relu(G0 + G1 + b1)  (1024x4096, bf16 planes -> bf16)
__global__ __launch_bounds__(256) void hfuse(
    const ushort4* __restrict__ G0, const ushort4* __restrict__ G1,
    const float* __restrict__ b1, ushort4* __restrict__ hb) {
  int i = blockIdx.x * 256 + threadIdx.x;       // 1048576 u4
  ushort4 a = G0[i], b = G1[i];
  const float4 bv = *(const float4*)(b1 + ((i & 1023) << 2));
  ushort4 o;
  o.x = f2bf(fmaxf(bf2f(a.x) + bf2f(b.x) + bv.x, 0.f));
  o.y = f2bf(fmaxf(bf2f(a.y) + bf2f(b.y) + bv.y, 0.f));
  o.z = f2bf(fmaxf(bf2f(a.z) + bf2f(b.z) + bv.z, 0.f));
  o.w = f2bf(fmaxf(bf2f(a.w) + bf2f(b.w) + bv.w, 0.f));
  hb[i] = o;
}

// ---------------- out = Q0+Q1+Q2+Q3 + b2   (1024x2048, bf16 planes -> f32)
__global__ __launch_bounds__(256) void reduce_out4(
    const ushort4* __restrict__ Q0, const ushort4* __restrict__ Q1,
    const ushort4* __restrict__ Q2, const ushort4* __restrict__ Q3,
    const float* __restrict__ b2, float4* __restrict__ out) {
  int i = blockIdx.x * 256 + threadIdx.x;       // 524288 u4
  ushort4 a = Q0[i], b = Q1[i], c = Q2[i], d = Q3[i];
  const float4 bb = *(const float4*)(b2 + ((i & 511) << 2));
  float4 o;
  o.x = bf2f(a.x) + bf2f(b.x) + bf2f(c.x) + bf2f(d.x) + bb.x;
  o.y = bf2f(a.y) + bf2f(b.y) + bf2f(c.y) + bf2f(d.y) + bb.y;
  o.z = bf2f(a.z) + bf2f(b.z) + bf2f(c.z) + bf2f(d.z) + bb.z;
  o.w = bf2f(a.w) + bf2f(b.w) + bf2f(c.w) + bf2f(d.w) + bb.w;
  out[i] = o;
}

extern "C" void kernel_launch(void* const* d_in, const int* in_sizes, int n_in,
                              void* d_out, int out_size, void* d_ws, size_t ws_size,
                              hipStream_t stream) {
  const float* x     = (const float*)d_in[0];
  const float* V     = (const float*)d_in[1];
  const float* W1_0  = (const float*)d_in[2];
  const float* b1_0  = (const float*)d_in[3];
  const float* W2_0  = (const float*)d_in[4];
  const float* b2_0  = (const float*)d_in[5];
  const float* BB_W1 = (const float*)d_in[6];
  const int*   Pi_W1 = (const int*)d_in[7];
  const float* GG_W1 = (const float*)d_in[8];
  const float* BB_b1 = (const float*)d_in[9];
  const int*   Pi_b1 = (const int*)d_in[10];
  const float* GG_b1 = (const float*)d_in[11];
  const float* BB_W2 = (const float*)d_in[12];
  const int*   Pi_W2 = (const int*)d_in[13];
  const float* GG_W2 = (const float*)d_in[14];
  const float* BB_b2 = (const float*)d_in[15];
  const int*   Pi_b2 = (const int*)d_in[16];
  const float* GG_b2 = (const float*)d_in[17];
  float* out = (float*)d_out;

  const size_t MB = 1048576ull;
  char* ws = (char*)d_ws;
  // inter1@0 / inter2@16 die after ff_pass2; G planes (gemm1, 8MB each) alias
  // inter1; Q planes (gemm2, 4MB each) alias inter2.
  ushort* inter1 = (ushort*)(ws);
  ushort* G0     = (ushort*)(ws);
  ushort* G1     = (ushort*)(ws + 8 * MB);
  ushort* inter2 = (ushort*)(ws + 16 * MB);
  ushort* Q0     = (ushort*)(ws + 16 * MB);
  ushort* Q1     = (ushort*)(ws + 20 * MB);
  ushort* Q2     = (ushort*)(ws + 24 * MB);
  ushort* Q3     = (ushort*)(ws + 28 * MB);
  ushort* W1b    = (ushort*)(ws + 32 * MB);
  ushort* W2b    = (ushort*)(ws + 48 * MB);
  ushort* xb     = (ushort*)(ws + 64 * MB);
  ushort* hb     = (ushort*)(ws + 68 * MB);
  char*   S      = ws + 76 * MB;
  float*  t1     = (float*)(S);
  float*  t2     = (float*)(S + 4096);
  float*  b1     = (float*)(S + 8192);
  float*  b2     = (float*)(S + 8192 + 16384);
  float*  parts  = (float*)(S + 8192 + 16384 + 8192);   // 2048 floats

  prep<<<2052, 256, 0, stream>>>((const float4*)x, (ushort4*)xb, V,
                                 BB_W1, BB_W2, t1, t2,
                                 BB_b1, Pi_b1, GG_b1, b1_0,
                                 BB_b2, Pi_b2, GG_b2, b2_0, b1, b2);

  ff_pass1<<<2048, 256, 0, stream>>>(Pi_W1, GG_W1, Pi_W2, GG_W2, t1, t2,
                                     inter1, inter2, parts);
  ff_pass2<<<256, 512, 0, stream>>>(inter1, inter2, W1_0, W2_0, parts, W1b, W2b);

  // gemm1: x @ W1b^T, K=2048 split-K2 -> G0,G1 (512 blocks, 2/CU)
  gemm_sp<16><<<dim3(32, 8, 2), 256, 0, stream>>>(xb, W1b, G0, G1, nullptr, nullptr,
                                                  1024, 4096, 2048);
  // h = relu(G0+G1+b1)
  hfuse<<<4096, 256, 0, stream>>>((const ushort4*)G0, (const ushort4*)G1, b1,
                                  (ushort4*)hb);
  // gemm2: h @ W2b^T, K=4096 split-K4 -> Q0..Q3 (512 blocks, 2/CU)
  gemm_sp<16><<<dim3(16, 8, 4), 256, 0, stream>>>(hb, W2b, Q0, Q1, Q2, Q3,
                                                  1024, 2048, 4096);
  // out = Q0+Q1+Q2+Q3 + b2
  reduce_out4<<<2048, 256, 0, stream>>>((const ushort4*)Q0, (const ushort4*)Q1,
                                        (const ushort4*)Q2, (const ushort4*)Q3,
                                        b2, (float4*)out);
}